// Round 15
// baseline (463.493 us; speedup 1.0000x reference)
//
#include <hip/hip_runtime.h>
#include <hip/hip_bf16.h>
#include <math.h>

using short8 = __attribute__((ext_vector_type(8))) short;
using f32x4  = __attribute__((ext_vector_type(4))) float;

#define NREP 32   // BN-stats replica buckets (contention /32)

__device__ __forceinline__ unsigned short f2bf(float x) {
    return __builtin_bit_cast(unsigned short, __float2bfloat16(x));
}
__device__ __forceinline__ float bf2f(unsigned short u) {
    unsigned int x = ((unsigned int)u) << 16;
    return __builtin_bit_cast(float, x);
}
// packed hi/lo bf16 in one u32: bits[15:0]=hi (main), bits[31:16]=lo (residual)
__device__ __forceinline__ unsigned int pack2(float v) {
    unsigned short h = f2bf(v);
    unsigned short l = f2bf(v - bf2f(h));
    return (unsigned int)h | ((unsigned int)l << 16);
}
__device__ __forceinline__ float unpack2(unsigned int u) {
    return bf2f((unsigned short)(u & 0xffff)) + bf2f((unsigned short)(u >> 16));
}

#define MFMA16(A,B,C) __builtin_amdgcn_mfma_f32_16x16x32_bf16((A),(B),(C),0,0,0)

// ---------------- CSR build (rank-based: ONE atomic pass) ----------------
__global__ __launch_bounds__(256) void k_fillR(const int* __restrict__ ei, int* __restrict__ cnt,
                                               int* __restrict__ rank, int E) {
    int e = blockIdx.x * blockDim.x + threadIdx.x;
    if (e < E) rank[e] = atomicAdd(&cnt[ei[E + e]], 1);
}

__global__ __launch_bounds__(256) void k_scanA(const int* __restrict__ cnt, int* __restrict__ offs,
                                               int* __restrict__ bsum, int N) {
    __shared__ int s[256];
    int i = blockIdx.x * 256 + threadIdx.x;
    int v = (i < N) ? cnt[i] : 0;
    s[threadIdx.x] = v;
    __syncthreads();
    #pragma unroll
    for (int d = 1; d < 256; d <<= 1) {
        int t = (threadIdx.x >= d) ? s[threadIdx.x - d] : 0;
        __syncthreads();
        s[threadIdx.x] += t;
        __syncthreads();
    }
    if (i < N) offs[i] = s[threadIdx.x] - v;
    if (threadIdx.x == 255) bsum[blockIdx.x] = s[255];
}

__global__ __launch_bounds__(256) void k_scanB(int* __restrict__ bsum, int nb) {
    __shared__ int s[256];
    int v = (threadIdx.x < nb) ? bsum[threadIdx.x] : 0;
    s[threadIdx.x] = v;
    __syncthreads();
    #pragma unroll
    for (int d = 1; d < 256; d <<= 1) {
        int t = (threadIdx.x >= d) ? s[threadIdx.x - d] : 0;
        __syncthreads();
        s[threadIdx.x] += t;
        __syncthreads();
    }
    if (threadIdx.x < nb) bsum[threadIdx.x] = s[threadIdx.x] - v;
}

__global__ __launch_bounds__(256) void k_scanC(int* __restrict__ offs, const int* __restrict__ bsum, int N) {
    int i = blockIdx.x * 256 + threadIdx.x;
    if (i < N) offs[i] += bsum[blockIdx.x];
}

__global__ __launch_bounds__(256) void k_scatter(const int* __restrict__ ei, const int* __restrict__ offs,
                                                 int* __restrict__ slotOf, int* __restrict__ srcSl, int E) {
    int e = blockIdx.x * blockDim.x + threadIdx.x;
    if (e < E) {
        int d = ei[E + e];
        int slot = offs[d] + slotOf[e];
        slotOf[e] = slot;
        srcSl[slot] = ei[e];
    }
}

// ---------------- pack x into hi/lo format ----------------
__global__ __launch_bounds__(256) void k_pack(const float* __restrict__ x,
                                              unsigned int* __restrict__ xP, int n) {
    int t = blockIdx.x * 256 + threadIdx.x;
    if (t < n) xP[t] = pack2(x[t]);
}

// ---------------- edge MLP a = relu(ea@w1+b1), packed hi/lo, slot order ----------------
__global__ __launch_bounds__(256) void k_a(
    const float* __restrict__ ea, const float* __restrict__ w1,
    const float* __restrict__ b1, const int* __restrict__ slotOf,
    unsigned int* __restrict__ aP, int E)
{
    int e = blockIdx.x * 256 + threadIdx.x;
    if (e >= E) return;
    const float4* p = (const float4*)(ea + (size_t)e * 8);
    float4 v0 = p[0], v1 = p[1];
    float eav[8] = {v0.x, v0.y, v0.z, v0.w, v1.x, v1.y, v1.z, v1.w};
    float a[16];
    #pragma unroll
    for (int k = 0; k < 16; k++) a[k] = b1[k];
    #pragma unroll
    for (int q = 0; q < 8; q++) {
        float ev = eav[q];
        #pragma unroll
        for (int k = 0; k < 16; k++) a[k] += ev * w1[q * 16 + k];
    }
    unsigned int pk[16];
    #pragma unroll
    for (int k = 0; k < 16; k++) pk[k] = pack2(fmaxf(a[k], 0.f));
    int slot = slotOf[e];
    uint4* o = (uint4*)(aP + (size_t)slot * 16);
    o[0] = make_uint4(pk[0], pk[1], pk[2], pk[3]);
    o[1] = make_uint4(pk[4], pk[5], pk[6], pk[7]);
    o[2] = make_uint4(pk[8], pk[9], pk[10], pk[11]);
    o[3] = make_uint4(pk[12], pk[13], pk[14], pk[15]);
}

// ---------------- combined weight prep: decoder frags (t<1920) + W2cat (t<4224) ----------
__global__ void k_wpreps(const float* __restrict__ dw0, const float* __restrict__ dw1,
                         const float* __restrict__ dw2, const float* __restrict__ dw3,
                         const float* __restrict__ dw4, unsigned short* __restrict__ wfrag,
                         const float* __restrict__ w2, const float* __restrict__ b2,
                         const float* __restrict__ r0, const float* __restrict__ r1,
                         const float* __restrict__ r2, const float* __restrict__ r3,
                         unsigned short* __restrict__ wf2)
{
    int tid = blockIdx.x * 256 + threadIdx.x;
    if (tid < 1920) {
        int f = tid >> 6, lane = tid & 63, g = lane >> 4, c = lane & 15;
        float v[8];
        if (f < 4) {
            int mt = f;
            #pragma unroll
            for (int j = 0; j < 8; j++) v[j] = dw0[(8*g + j) * 64 + 16*mt + c];
        } else if (f < 28) {
            int fl = f - 4;
            const float* W = (fl >> 3) == 0 ? dw1 : ((fl >> 3) == 1 ? dw2 : dw3);
            int mt = (fl & 7) >> 1, kt = fl & 1;
            #pragma unroll
            for (int j = 0; j < 8; j++) {
                int in = 16*(2*kt + (j>>2)) + 4*g + (j&3);
                v[j] = W[in * 64 + 16*mt + c];
            }
        } else {
            int kt = f - 28;
            #pragma unroll
            for (int j = 0; j < 8; j++) {
                int in = 16*(2*kt + (j>>2)) + 4*g + (j&3);
                v[j] = (c < 8) ? dw4[in * 8 + c] : 0.f;
            }
        }
        unsigned short* o = wfrag + (size_t)tid * 8;
        #pragma unroll
        for (int j = 0; j < 8; j++) o[j] = f2bf(v[j]);
    } else if (tid < 1920 + 2304) {
        int t2 = tid - 1920;
        int l = t2 / 576, rem = t2 % 576;
        int t = rem / 64, lane = rem % 64;
        int g = lane >> 4, o = lane & 15;
        const float* roots[4] = {r0, r1, r2, r3};
        unsigned short hi8[8], lo8[8];
        #pragma unroll
        for (int j = 0; j < 8; j++) {
            int kp = 32 * t + 8 * g + j;
            int i = kp / 18, k = kp % 18;
            float v;
            if (k < 16)      v = w2[k * 256 + i * 16 + o];
            else if (k == 16) v = b2[i * 16 + o];
            else              v = roots[l][i * 16 + o];
            unsigned short h = f2bf(v);
            hi8[j] = h;
            lo8[j] = f2bf(v - bf2f(h));
        }
        unsigned short* oh = wf2 + (size_t)l * 9216 + (t * 2 + 0) * 512 + lane * 8;
        unsigned short* ol = wf2 + (size_t)l * 9216 + (t * 2 + 1) * 512 + lane * 8;
        #pragma unroll
        for (int j = 0; j < 8; j++) { oh[j] = hi8[j]; ol[j] = lo8[j]; }
    }
}

// ---------------- fused conv layer v7: replicated BN-stats (verified R13) ------------
template<int BNPREV>
__global__ __launch_bounds__(256) void k_fuse3(
    const unsigned int* __restrict__ hP, const float* __restrict__ statsPrev,
    const float* __restrict__ gPrev, const float* __restrict__ bePrev,
    const int* __restrict__ offs, const int* __restrict__ cnt,
    const int* __restrict__ srcSl, const unsigned int* __restrict__ aP,
    const unsigned short* __restrict__ wfragL, const float* __restrict__ cb,
    unsigned int* __restrict__ houtP, float* __restrict__ statsCur,
    int N, float invN)
{
    __shared__ unsigned short Bl[2][16][296];
    __shared__ float scsh[32];
    __shared__ float ssum[32];
    int tid = threadIdx.x;
    int w = __builtin_amdgcn_readfirstlane(tid >> 6);   // R4 lesson: keep scalar
    int lane = tid & 63;
    int g = lane >> 4, i = lane & 15;
    if (BNPREV) {
        if (tid < 32) {
            float s = 0.f;
            #pragma unroll
            for (int r = 0; r < NREP; r++) s += statsPrev[r * 32 + tid];
            ssum[tid] = s;
        }
        __syncthreads();
        if (tid < 16) {
            float m = ssum[tid] * invN;
            float var = ssum[16 + tid] * invN - m * m;
            float sc = gPrev[tid] * rsqrtf(var + 1e-5f);
            scsh[tid] = sc;
            scsh[16 + tid] = bePrev[tid] - m * sc;
        }
        __syncthreads();
    }
    float scC = BNPREV ? scsh[i] : 1.f;
    float shC = BNPREV ? scsh[16 + i] : 0.f;
    int base = blockIdx.x * 16;

    const f32x4 zero4 = {0.f, 0.f, 0.f, 0.f};
    short8 ones;
    #pragma unroll
    for (int j = 0; j < 8; j++) ones[j] = (short)0x3F80;

    int st4[4], dg4[4];
    #pragma unroll
    for (int q = 0; q < 4; q++) {
        int node = base + w * 4 + q;
        bool v = node < N;
        st4[q] = v ? offs[node] : 0;
        dg4[q] = v ? cnt[node] : 0;
    }
    int mx = max(max(dg4[0], dg4[1]), max(dg4[2], dg4[3]));

    if (mx <= 32) {
        unsigned int aw[4][8], hw[4][8];
        #pragma unroll
        for (int q = 0; q < 4; q++) {
            #pragma unroll
            for (int j = 0; j < 8; j++) {
                int sl = 8 * g + j;
                bool ok = sl < dg4[q];
                size_t slc = ok ? (size_t)(st4[q] + sl) : 0;
                int src = srcSl[slc];
                unsigned int a = aP[slc * 16 + i];
                unsigned int h = hP[(size_t)src * 16 + i];
                aw[q][j] = ok ? a : 0u;
                hw[q][j] = ok ? h : 0u;
            }
        }
        #pragma unroll
        for (int q = 0; q < 4; q++) {
            short8 ah, al, hh, hl;
            #pragma unroll
            for (int j = 0; j < 8; j++) {
                ah[j] = (short)(aw[q][j] & 0xffffu);
                al[j] = (short)(aw[q][j] >> 16);
                hh[j] = (short)(hw[q][j] & 0xffffu);
                hl[j] = (short)(hw[q][j] >> 16);
            }
            f32x4 accM  = MFMA16(ah, hh, zero4);
            f32x4 accC  = MFMA16(ah, hl, zero4);
            accC        = MFMA16(al, hh, accC);
            f32x4 accSa = MFMA16(ah, ones, zero4);
            accSa       = MFMA16(al, ones, accSa);
            f32x4 accSh = MFMA16(ones, hh, zero4);
            accSh       = MFMA16(ones, hl, accSh);

            int node = base + w * 4 + q;
            int nvalid = node < N;
            int nl = w * 4 + q;
            float v0 = scC * (accM[0] + accC[0]) + shC * accSa[0];
            float v1 = scC * (accM[1] + accC[1]) + shC * accSa[1];
            float v2 = scC * (accM[2] + accC[2]) + shC * accSa[2];
            float v3 = scC * (accM[3] + accC[3]) + shC * accSa[3];
            unsigned short h0 = f2bf(v0), h1 = f2bf(v1), h2 = f2bf(v2), h3 = f2bf(v3);
            unsigned short l0 = f2bf(v0 - bf2f(h0)), l1 = f2bf(v1 - bf2f(h1));
            unsigned short l2 = f2bf(v2 - bf2f(h2)), l3 = f2bf(v3 - bf2f(h3));
            *(unsigned int*)&Bl[0][nl][i*18 + 4*g]     = (unsigned int)h0 | ((unsigned int)h1 << 16);
            *(unsigned int*)&Bl[0][nl][i*18 + 4*g + 2] = (unsigned int)h2 | ((unsigned int)h3 << 16);
            *(unsigned int*)&Bl[1][nl][i*18 + 4*g]     = (unsigned int)l0 | ((unsigned int)l1 << 16);
            *(unsigned int*)&Bl[1][nl][i*18 + 4*g + 2] = (unsigned int)l2 | ((unsigned int)l3 << 16);
            if (g == 0) {
                float v = scC * accSh[0] + shC * (float)dg4[q];
                unsigned short hh16 = f2bf(v);
                Bl[0][nl][i*18 + 16] = hh16;
                Bl[1][nl][i*18 + 16] = f2bf(v - bf2f(hh16));
            } else if (g == 1) {
                float hn = unpack2(hP[(size_t)(nvalid ? node : 0) * 16 + i]);
                float v = scC * hn + shC;
                unsigned short hh17 = f2bf(v);
                Bl[0][nl][i*18 + 17] = hh17;
                Bl[1][nl][i*18 + 17] = f2bf(v - bf2f(hh17));
            }
        }
    } else {
        for (int q = 0; q < 4; q++) {
            int node = base + w * 4 + q;
            int nvalid = node < N;
            int start = st4[q], deg = dg4[q];
            f32x4 accM  = zero4;
            f32x4 accC  = zero4;
            f32x4 accSa = zero4;
            f32x4 accSh = zero4;
            int nch = (deg + 31) >> 5;
            for (int ch = 0; ch < nch; ch++) {
                unsigned int aw[8], hw[8];
                #pragma unroll
                for (int j = 0; j < 8; j++) {
                    int sl = ch * 32 + 8 * g + j;
                    bool ok = sl < deg;
                    size_t slc = ok ? (size_t)(start + sl) : 0;
                    unsigned int a = aP[slc * 16 + i];
                    int src = srcSl[slc];
                    unsigned int h = hP[(size_t)src * 16 + i];
                    aw[j] = ok ? a : 0u;
                    hw[j] = ok ? h : 0u;
                }
                short8 ah, al, hh, hl;
                #pragma unroll
                for (int j = 0; j < 8; j++) {
                    ah[j] = (short)(aw[j] & 0xffffu);
                    al[j] = (short)(aw[j] >> 16);
                    hh[j] = (short)(hw[j] & 0xffffu);
                    hl[j] = (short)(hw[j] >> 16);
                }
                accM  = MFMA16(ah, hh, accM);
                accC  = MFMA16(ah, hl, accC);
                accC  = MFMA16(al, hh, accC);
                accSa = MFMA16(ah, ones, accSa);
                accSa = MFMA16(al, ones, accSa);
                accSh = MFMA16(ones, hh, accSh);
                accSh = MFMA16(ones, hl, accSh);
            }
            int nl = w * 4 + q;
            float v0 = scC * (accM[0] + accC[0]) + shC * accSa[0];
            float v1 = scC * (accM[1] + accC[1]) + shC * accSa[1];
            float v2 = scC * (accM[2] + accC[2]) + shC * accSa[2];
            float v3 = scC * (accM[3] + accC[3]) + shC * accSa[3];
            unsigned short h0 = f2bf(v0), h1 = f2bf(v1), h2 = f2bf(v2), h3 = f2bf(v3);
            unsigned short l0 = f2bf(v0 - bf2f(h0)), l1 = f2bf(v1 - bf2f(h1));
            unsigned short l2 = f2bf(v2 - bf2f(h2)), l3 = f2bf(v3 - bf2f(h3));
            *(unsigned int*)&Bl[0][nl][i*18 + 4*g]     = (unsigned int)h0 | ((unsigned int)h1 << 16);
            *(unsigned int*)&Bl[0][nl][i*18 + 4*g + 2] = (unsigned int)h2 | ((unsigned int)h3 << 16);
            *(unsigned int*)&Bl[1][nl][i*18 + 4*g]     = (unsigned int)l0 | ((unsigned int)l1 << 16);
            *(unsigned int*)&Bl[1][nl][i*18 + 4*g + 2] = (unsigned int)l2 | ((unsigned int)l3 << 16);
            if (g == 0) {
                float v = scC * accSh[0] + shC * (float)deg;
                unsigned short hh16 = f2bf(v);
                Bl[0][nl][i*18 + 16] = hh16;
                Bl[1][nl][i*18 + 16] = f2bf(v - bf2f(hh16));
            } else if (g == 1) {
                float hn = unpack2(hP[(size_t)(nvalid ? node : 0) * 16 + i]);
                float v = scC * hn + shC;
                unsigned short hh17 = f2bf(v);
                Bl[0][nl][i*18 + 17] = hh17;
                Bl[1][nl][i*18 + 17] = f2bf(v - bf2f(hh17));
            }
        }
    }
    __syncthreads();

    if (w != 0) return;

    float cbv = cb[i];
    f32x4 acc0 = {cbv, cbv, cbv, cbv};
    f32x4 acc1 = zero4;
    f32x4 acc2 = zero4;
    const short8* wf = (const short8*)wfragL;
    #pragma unroll
    for (int t = 0; t < 9; t++) {
        short8 whi = wf[(t*2+0)*64 + lane];
        short8 wlo = wf[(t*2+1)*64 + lane];
        short8 ahi = *(const short8*)&Bl[0][i][32*t + 8*g];
        short8 alo = *(const short8*)&Bl[1][i][32*t + 8*g];
        acc0 = MFMA16(ahi, whi, acc0);
        acc1 = MFMA16(ahi, wlo, acc1);
        acc2 = MFMA16(alo, whi, acc2);
    }

    float s1 = 0.f, s2 = 0.f;
    #pragma unroll
    for (int rr = 0; rr < 4; rr++) {
        int n2 = base + 4*g + rr;
        float v = fmaxf(acc0[rr] + acc1[rr] + acc2[rr], 0.f);
        if (n2 < N) {
            houtP[(size_t)n2 * 16 + i] = pack2(v);
            s1 += v; s2 += v * v;
        }
    }
    s1 += __shfl_xor(s1, 16); s1 += __shfl_xor(s1, 32);
    s2 += __shfl_xor(s2, 16); s2 += __shfl_xor(s2, 32);
    if (lane < 16) {
        float* repl = statsCur + (blockIdx.x & (NREP - 1)) * 32;
        atomicAdd(&repl[i], s1);
        atomicAdd(&repl[16 + i], s2);
    }
}

// ---------------- mu / logvar / reparameterize (BN stats from replicas) ----
__global__ __launch_bounds__(256) void k_z(
    const unsigned int* __restrict__ hP, const float* __restrict__ stats4,
    const float* __restrict__ g4, const float* __restrict__ be4,
    const float* __restrict__ mu_w, const float* __restrict__ mu_b,
    const float* __restrict__ lv_w, const float* __restrict__ lv_b,
    const float* __restrict__ eps, float* __restrict__ z, int N, float invN)
{
    __shared__ float scsh[32];
    __shared__ float ssum[32];
    int tid = threadIdx.x;
    if (tid < 32) {
        float s = 0.f;
        #pragma unroll
        for (int r = 0; r < NREP; r++) s += stats4[r * 32 + tid];
        ssum[tid] = s;
    }
    __syncthreads();
    if (tid < 16) {
        float m = ssum[tid] * invN;
        float var = ssum[16 + tid] * invN - m * m;
        float sc = g4[tid] * rsqrtf(var + 1e-5f);
        scsh[tid] = sc;
        scsh[16 + tid] = be4[tid] - m * sc;
    }
    __syncthreads();
    int t = blockIdx.x * 256 + tid;
    if (t >= N * 16) return;
    int n = t >> 4, o = t & 15;
    const uint4* hp4 = (const uint4*)(hP + (size_t)n * 16);
    uint4 u0 = hp4[0], u1 = hp4[1], u2 = hp4[2], u3 = hp4[3];
    unsigned int uu[16] = {u0.x,u0.y,u0.z,u0.w, u1.x,u1.y,u1.z,u1.w,
                           u2.x,u2.y,u2.z,u2.w, u3.x,u3.y,u3.z,u3.w};
    float mu = mu_b[o], lv = lv_b[o];
    #pragma unroll
    for (int j = 0; j < 16; j++) {
        float hv = unpack2(uu[j]) * scsh[j] + scsh[16 + j];
        mu += hv * mu_w[j * 16 + o];
        lv += hv * lv_w[j * 16 + o];
    }
    lv = fminf(lv, 10.f);
    z[t] = mu + eps[t] * expf(0.5f * lv);
}

// ---------------- MFMA decoder v3: 2 tiles/wave, depth-1 prefetch, VGPR<=128 ------------
// __launch_bounds__(256,4): pins allocator at <=128 VGPR -> 4 waves/SIMD with 2 chains
// each (8 independent chains/SIMD vs R13's 4). R14 lesson: 144 VGPR dropped to 3
// waves/SIMD and ate the ILP gain.
#define REPACK1(ACC, A2) do { \
    float av[16]; \
    _Pragma("unroll") for (int mt = 0; mt < 4; mt++) { \
        _Pragma("unroll") for (int r = 0; r < 4; r++) av[mt*4 + r] = ACC[mt][r]; } \
    _Pragma("unroll") for (int kt = 0; kt < 2; kt++) { \
        _Pragma("unroll") for (int j = 0; j < 8; j++) \
            A2[kt][j] = (short)f2bf(fmaxf(av[(2*kt + (j>>2))*4 + (j&3)], 0.f)); } \
} while (0)

#define DENSE2(OFS, DB) do { \
    _Pragma("unroll") for (int mt = 0; mt < 4; mt++) { \
        f32x4 bv = *(const f32x4*)((DB) + 16*mt + 4*g); \
        accA[mt] = bv; accB[mt] = bv; } \
    _Pragma("unroll") for (int mt = 0; mt < 4; mt++) { \
        short8 wv = wf[((OFS) + mt*2)*64 + lane]; \
        accA[mt] = MFMA16(wv, a2A[0], accA[mt]); \
        accB[mt] = MFMA16(wv, a2B[0], accB[mt]); } \
    _Pragma("unroll") for (int mt = 0; mt < 4; mt++) { \
        short8 wv = wf[((OFS) + mt*2 + 1)*64 + lane]; \
        accA[mt] = MFMA16(wv, a2A[1], accA[mt]); \
        accB[mt] = MFMA16(wv, a2B[1], accB[mt]); } \
    REPACK1(accA, a2A); \
    REPACK1(accB, a2B); \
} while (0)

__global__ __launch_bounds__(256, 4) void k_dec(
    const float* __restrict__ z, const int* __restrict__ ei,
    const unsigned short* __restrict__ wfrag,
    const float* __restrict__ db0, const float* __restrict__ db1,
    const float* __restrict__ db2, const float* __restrict__ db3,
    const float* __restrict__ db4,
    float* __restrict__ out, int E, int TP, int totalTiles)
{
    int wid = blockIdx.x * 4 + (threadIdx.x >> 6);
    int lane = threadIdx.x & 63;
    int g = lane >> 4, c = lane & 15;
    int totalPairs = (totalTiles + 1) >> 1;
    int p0 = wid * TP;
    if (p0 >= totalPairs) return;
    int p1 = min(p0 + TP, totalPairs);

    const short8* wf = (const short8*)wfrag;
    int eiOfs = (g < 2) ? 0 : E;
    int zofs = (g & 1) * 8;

    // depth-1 pipeline: only node INDICES prefetched one pair ahead
    int nodeA = ei[eiOfs + min(p0*32 + c, E - 1)];
    int nodeB = ei[eiOfs + min(p0*32 + 16 + c, E - 1)];

    for (int p = p0; p < p1; ++p) {
        // load z for current pair (L2-resident; latency hidden by 4 waves/SIMD)
        f32x4 zvA0 = *(const f32x4*)(z + (size_t)nodeA * 16 + zofs);
        f32x4 zvA1 = *(const f32x4*)(z + (size_t)nodeA * 16 + zofs + 4);
        f32x4 zvB0 = *(const f32x4*)(z + (size_t)nodeB * 16 + zofs);
        f32x4 zvB1 = *(const f32x4*)(z + (size_t)nodeB * 16 + zofs + 4);
        // prefetch next pair's node indices
        if (p + 1 < p1) {
            nodeA = ei[eiOfs + min((p+1)*32 + c, E - 1)];
            nodeB = ei[eiOfs + min((p+1)*32 + 16 + c, E - 1)];
        }

        short8 afA, afB;
        #pragma unroll
        for (int j = 0; j < 4; j++) {
            afA[j]     = (short)f2bf(zvA0[j]);
            afA[4 + j] = (short)f2bf(zvA1[j]);
            afB[j]     = (short)f2bf(zvB0[j]);
            afB[4 + j] = (short)f2bf(zvB1[j]);
        }
        f32x4 accA[4], accB[4];
        short8 a2A[2], a2B[2];
        #pragma unroll
        for (int mt = 0; mt < 4; mt++) {
            f32x4 bv = *(const f32x4*)(db0 + 16*mt + 4*g);
            accA[mt] = bv; accB[mt] = bv;
        }
        #pragma unroll
        for (int mt = 0; mt < 4; mt++) {
            short8 wv = wf[mt*64 + lane];
            accA[mt] = MFMA16(wv, afA, accA[mt]);
            accB[mt] = MFMA16(wv, afB, accB[mt]);
        }
        REPACK1(accA, a2A);
        REPACK1(accB, a2B);

        DENSE2(4,  db1);
        DENSE2(12, db2);
        DENSE2(20, db3);

        f32x4 o4A, o4B;
        if (g < 2) { o4A = *(const f32x4*)(db4 + 4*g); }
        else { o4A[0]=0.f; o4A[1]=0.f; o4A[2]=0.f; o4A[3]=0.f; }
        o4B = o4A;
        {
            short8 w0 = wf[28*64 + lane];
            short8 w1v = wf[29*64 + lane];
            o4A = MFMA16(w0, a2A[0], o4A);
            o4B = MFMA16(w0, a2B[0], o4B);
            o4A = MFMA16(w1v, a2A[1], o4A);
            o4B = MFMA16(w1v, a2B[1], o4B);
        }

        int eA = p*32 + c;
        int eB = p*32 + 16 + c;
        if (g < 2 && eA < E) *(f32x4*)(out + (size_t)eA * 8 + 4*g) = o4A;
        if (g < 2 && eB < E) *(f32x4*)(out + (size_t)eB * 8 + 4*g) = o4B;
    }
}

// ---------------- launch ----------------
extern "C" void kernel_launch(void* const* d_in, const int* in_sizes, int n_in,
                              void* d_out, int out_size, void* d_ws, size_t ws_size,
                              hipStream_t stream)
{
    const float* x   = (const float*)d_in[0];
    const int*   ei  = (const int*)d_in[1];
    const float* ea  = (const float*)d_in[2];
    const float* eps = (const float*)d_in[3];
    const float* w1  = (const float*)d_in[4];
    const float* b1  = (const float*)d_in[5];
    const float* w2  = (const float*)d_in[6];
    const float* b2  = (const float*)d_in[7];
    const float* root[4]; const float* cb[4]; const float* g[4]; const float* be[4];
    for (int l = 0; l < 4; l++) {
        root[l] = (const float*)d_in[8 + 4*l];
        cb[l]   = (const float*)d_in[9 + 4*l];
        g[l]    = (const float*)d_in[10 + 4*l];
        be[l]   = (const float*)d_in[11 + 4*l];
    }
    const float* mu_w = (const float*)d_in[24];
    const float* mu_b = (const float*)d_in[25];
    const float* lv_w = (const float*)d_in[26];
    const float* lv_b = (const float*)d_in[27];
    const float* dw[5]; const float* db[5];
    for (int i = 0; i < 5; i++) {
        dw[i] = (const float*)d_in[28 + 2*i];
        db[i] = (const float*)d_in[29 + 2*i];
    }
    float* out = (float*)d_out;

    int N = in_sizes[0] / 16;
    int E = in_sizes[2] / 8;
    float invN = 1.0f / N;

    // ---- workspace layout ----
    int*   cnt      = (int*)d_ws;                       // N
    float* statsRep = (float*)(cnt + N);                // 4 x NREP x 32
    int*   offs     = (int*)(statsRep + 4 * NREP * 32); // N
    int*   bsum     = offs + N;                         // 256
    int*   slotOf   = bsum + 256;                       // E (rank, then slot)
    int*   srcSl    = slotOf + E;                       // E
    unsigned int* aP  = (unsigned int*)(srcSl + E);     // E*16 (packed)
    unsigned int* xP  = aP + (size_t)E * 16;            // N*16 (packed)
    unsigned int* hA  = xP + (size_t)N * 16;            // N*16 (packed)
    unsigned int* hB  = hA + (size_t)N * 16;            // N*16 (packed)
    float* zbuf     = (float*)(hB + (size_t)N * 16);    // N*16
    unsigned short* wfrag  = (unsigned short*)(zbuf + (size_t)N * 16); // 15360
    unsigned short* wfrag2 = wfrag + 15360;             // 36864

    int nbScan = (N + 255) / 256;

    (void)hipMemsetAsync(cnt, 0, ((size_t)N + 4 * NREP * 32) * sizeof(int), stream);

    k_wpreps<<<17, 256, 0, stream>>>(dw[0], dw[1], dw[2], dw[3], dw[4], wfrag,
                                     w2, b2, root[0], root[1], root[2], root[3], wfrag2);
    k_pack<<<(N * 16 + 255) / 256, 256, 0, stream>>>(x, xP, N * 16);

    k_fillR<<<(E + 255) / 256, 256, 0, stream>>>(ei, cnt, slotOf, E);
    k_scanA<<<nbScan, 256, 0, stream>>>(cnt, offs, bsum, N);
    k_scanB<<<1, 256, 0, stream>>>(bsum, nbScan);
    k_scanC<<<nbScan, 256, 0, stream>>>(offs, bsum, N);
    k_scatter<<<(E + 255) / 256, 256, 0, stream>>>(ei, offs, slotOf, srcSl, E);

    k_a<<<(E + 255) / 256, 256, 0, stream>>>(ea, w1, b1, slotOf, aP, E);

    int nbF = (N + 15) / 16;
    float* sr0 = statsRep + 0 * NREP * 32;
    float* sr1 = statsRep + 1 * NREP * 32;
    float* sr2 = statsRep + 2 * NREP * 32;
    float* sr3 = statsRep + 3 * NREP * 32;

    k_fuse3<0><<<nbF, 256, 0, stream>>>(xP, nullptr, nullptr, nullptr,
                                        offs, cnt, srcSl, aP,
                                        wfrag2 + 0 * 9216, cb[0], hA, sr0, N, invN);
    k_fuse3<1><<<nbF, 256, 0, stream>>>(hA, sr0, g[0], be[0],
                                        offs, cnt, srcSl, aP,
                                        wfrag2 + 1 * 9216, cb[1], hB, sr1, N, invN);
    k_fuse3<1><<<nbF, 256, 0, stream>>>(hB, sr1, g[1], be[1],
                                        offs, cnt, srcSl, aP,
                                        wfrag2 + 2 * 9216, cb[2], hA, sr2, N, invN);
    k_fuse3<1><<<nbF, 256, 0, stream>>>(hA, sr2, g[2], be[2],
                                        offs, cnt, srcSl, aP,
                                        wfrag2 + 3 * 9216, cb[3], hB, sr3, N, invN);

    k_z<<<(N * 16 + 255) / 256, 256, 0, stream>>>(hB, sr3, g[3], be[3],
                                                  mu_w, mu_b, lv_w, lv_b, eps, zbuf, N, invN);

    // decoder: 2 tiles/wave, depth-1 pipeline
    int totalTiles = (E + 15) >> 4;
    int totalPairs = (totalTiles + 1) >> 1;
    int TP = (totalPairs + 4095) / 4096;            // pairs per wave (~7)
    int wavesUsed = (totalPairs + TP - 1) / TP;
    int blocks = (wavesUsed + 3) / 4;
    k_dec<<<blocks, 256, 0, stream>>>(zbuf, ei, wfrag,
        db[0], db[1], db[2], db[3], db[4], out, E, TP, totalTiles);
}

// Round 16
// 273.690 us; speedup vs baseline: 1.6935x; 1.6935x over previous
//
#include <hip/hip_runtime.h>
#include <hip/hip_bf16.h>
#include <math.h>

using short8 = __attribute__((ext_vector_type(8))) short;
using f32x4  = __attribute__((ext_vector_type(4))) float;

#define NREP 32   // BN-stats replica buckets (contention /32)

__device__ __forceinline__ unsigned short f2bf(float x) {
    return __builtin_bit_cast(unsigned short, __float2bfloat16(x));
}
__device__ __forceinline__ float bf2f(unsigned short u) {
    unsigned int x = ((unsigned int)u) << 16;
    return __builtin_bit_cast(float, x);
}
// packed hi/lo bf16 in one u32: bits[15:0]=hi (main), bits[31:16]=lo (residual)
__device__ __forceinline__ unsigned int pack2(float v) {
    unsigned short h = f2bf(v);
    unsigned short l = f2bf(v - bf2f(h));
    return (unsigned int)h | ((unsigned int)l << 16);
}
__device__ __forceinline__ float unpack2(unsigned int u) {
    return bf2f((unsigned short)(u & 0xffff)) + bf2f((unsigned short)(u >> 16));
}

#define MFMA16(A,B,C) __builtin_amdgcn_mfma_f32_16x16x32_bf16((A),(B),(C),0,0,0)

// ---------------- CSR build (rank-based: ONE atomic pass) ----------------
__global__ __launch_bounds__(256) void k_fillR(const int* __restrict__ ei, int* __restrict__ cnt,
                                               int* __restrict__ rank, int E) {
    int e = blockIdx.x * blockDim.x + threadIdx.x;
    if (e < E) rank[e] = atomicAdd(&cnt[ei[E + e]], 1);
}

__global__ __launch_bounds__(256) void k_scanA(const int* __restrict__ cnt, int* __restrict__ offs,
                                               int* __restrict__ bsum, int N) {
    __shared__ int s[256];
    int i = blockIdx.x * 256 + threadIdx.x;
    int v = (i < N) ? cnt[i] : 0;
    s[threadIdx.x] = v;
    __syncthreads();
    #pragma unroll
    for (int d = 1; d < 256; d <<= 1) {
        int t = (threadIdx.x >= d) ? s[threadIdx.x - d] : 0;
        __syncthreads();
        s[threadIdx.x] += t;
        __syncthreads();
    }
    if (i < N) offs[i] = s[threadIdx.x] - v;
    if (threadIdx.x == 255) bsum[blockIdx.x] = s[255];
}

__global__ __launch_bounds__(256) void k_scanB(int* __restrict__ bsum, int nb) {
    __shared__ int s[256];
    int v = (threadIdx.x < nb) ? bsum[threadIdx.x] : 0;
    s[threadIdx.x] = v;
    __syncthreads();
    #pragma unroll
    for (int d = 1; d < 256; d <<= 1) {
        int t = (threadIdx.x >= d) ? s[threadIdx.x - d] : 0;
        __syncthreads();
        s[threadIdx.x] += t;
        __syncthreads();
    }
    if (threadIdx.x < nb) bsum[threadIdx.x] = s[threadIdx.x] - v;
}

__global__ __launch_bounds__(256) void k_scanC(int* __restrict__ offs, const int* __restrict__ bsum, int N) {
    int i = blockIdx.x * 256 + threadIdx.x;
    if (i < N) offs[i] += bsum[blockIdx.x];
}

__global__ __launch_bounds__(256) void k_scatter(const int* __restrict__ ei, const int* __restrict__ offs,
                                                 int* __restrict__ slotOf, int* __restrict__ srcSl, int E) {
    int e = blockIdx.x * blockDim.x + threadIdx.x;
    if (e < E) {
        int d = ei[E + e];
        int slot = offs[d] + slotOf[e];
        slotOf[e] = slot;
        srcSl[slot] = ei[e];
    }
}

// ---------------- pack x into hi/lo format ----------------
__global__ __launch_bounds__(256) void k_pack(const float* __restrict__ x,
                                              unsigned int* __restrict__ xP, int n) {
    int t = blockIdx.x * 256 + threadIdx.x;
    if (t < n) xP[t] = pack2(x[t]);
}

// ---------------- edge MLP a = relu(ea@w1+b1), packed hi/lo, slot order ----------------
__global__ __launch_bounds__(256) void k_a(
    const float* __restrict__ ea, const float* __restrict__ w1,
    const float* __restrict__ b1, const int* __restrict__ slotOf,
    unsigned int* __restrict__ aP, int E)
{
    int e = blockIdx.x * 256 + threadIdx.x;
    if (e >= E) return;
    const float4* p = (const float4*)(ea + (size_t)e * 8);
    float4 v0 = p[0], v1 = p[1];
    float eav[8] = {v0.x, v0.y, v0.z, v0.w, v1.x, v1.y, v1.z, v1.w};
    float a[16];
    #pragma unroll
    for (int k = 0; k < 16; k++) a[k] = b1[k];
    #pragma unroll
    for (int q = 0; q < 8; q++) {
        float ev = eav[q];
        #pragma unroll
        for (int k = 0; k < 16; k++) a[k] += ev * w1[q * 16 + k];
    }
    unsigned int pk[16];
    #pragma unroll
    for (int k = 0; k < 16; k++) pk[k] = pack2(fmaxf(a[k], 0.f));
    int slot = slotOf[e];
    uint4* o = (uint4*)(aP + (size_t)slot * 16);
    o[0] = make_uint4(pk[0], pk[1], pk[2], pk[3]);
    o[1] = make_uint4(pk[4], pk[5], pk[6], pk[7]);
    o[2] = make_uint4(pk[8], pk[9], pk[10], pk[11]);
    o[3] = make_uint4(pk[12], pk[13], pk[14], pk[15]);
}

// ---------------- combined weight prep: decoder frags (t<1920) + W2cat (t<4224) ----------
__global__ void k_wpreps(const float* __restrict__ dw0, const float* __restrict__ dw1,
                         const float* __restrict__ dw2, const float* __restrict__ dw3,
                         const float* __restrict__ dw4, unsigned short* __restrict__ wfrag,
                         const float* __restrict__ w2, const float* __restrict__ b2,
                         const float* __restrict__ r0, const float* __restrict__ r1,
                         const float* __restrict__ r2, const float* __restrict__ r3,
                         unsigned short* __restrict__ wf2)
{
    int tid = blockIdx.x * 256 + threadIdx.x;
    if (tid < 1920) {
        int f = tid >> 6, lane = tid & 63, g = lane >> 4, c = lane & 15;
        float v[8];
        if (f < 4) {
            int mt = f;
            #pragma unroll
            for (int j = 0; j < 8; j++) v[j] = dw0[(8*g + j) * 64 + 16*mt + c];
        } else if (f < 28) {
            int fl = f - 4;
            const float* W = (fl >> 3) == 0 ? dw1 : ((fl >> 3) == 1 ? dw2 : dw3);
            int mt = (fl & 7) >> 1, kt = fl & 1;
            #pragma unroll
            for (int j = 0; j < 8; j++) {
                int in = 16*(2*kt + (j>>2)) + 4*g + (j&3);
                v[j] = W[in * 64 + 16*mt + c];
            }
        } else {
            int kt = f - 28;
            #pragma unroll
            for (int j = 0; j < 8; j++) {
                int in = 16*(2*kt + (j>>2)) + 4*g + (j&3);
                v[j] = (c < 8) ? dw4[in * 8 + c] : 0.f;
            }
        }
        unsigned short* o = wfrag + (size_t)tid * 8;
        #pragma unroll
        for (int j = 0; j < 8; j++) o[j] = f2bf(v[j]);
    } else if (tid < 1920 + 2304) {
        int t2 = tid - 1920;
        int l = t2 / 576, rem = t2 % 576;
        int t = rem / 64, lane = rem % 64;
        int g = lane >> 4, o = lane & 15;
        const float* roots[4] = {r0, r1, r2, r3};
        unsigned short hi8[8], lo8[8];
        #pragma unroll
        for (int j = 0; j < 8; j++) {
            int kp = 32 * t + 8 * g + j;
            int i = kp / 18, k = kp % 18;
            float v;
            if (k < 16)      v = w2[k * 256 + i * 16 + o];
            else if (k == 16) v = b2[i * 16 + o];
            else              v = roots[l][i * 16 + o];
            unsigned short h = f2bf(v);
            hi8[j] = h;
            lo8[j] = f2bf(v - bf2f(h));
        }
        unsigned short* oh = wf2 + (size_t)l * 9216 + (t * 2 + 0) * 512 + lane * 8;
        unsigned short* ol = wf2 + (size_t)l * 9216 + (t * 2 + 1) * 512 + lane * 8;
        #pragma unroll
        for (int j = 0; j < 8; j++) { oh[j] = hi8[j]; ol[j] = lo8[j]; }
    }
}

// ---------------- fused conv layer v7: replicated BN-stats (verified R13) ------------
template<int BNPREV>
__global__ __launch_bounds__(256) void k_fuse3(
    const unsigned int* __restrict__ hP, const float* __restrict__ statsPrev,
    const float* __restrict__ gPrev, const float* __restrict__ bePrev,
    const int* __restrict__ offs, const int* __restrict__ cnt,
    const int* __restrict__ srcSl, const unsigned int* __restrict__ aP,
    const unsigned short* __restrict__ wfragL, const float* __restrict__ cb,
    unsigned int* __restrict__ houtP, float* __restrict__ statsCur,
    int N, float invN)
{
    __shared__ unsigned short Bl[2][16][296];
    __shared__ float scsh[32];
    __shared__ float ssum[32];
    int tid = threadIdx.x;
    int w = __builtin_amdgcn_readfirstlane(tid >> 6);   // R4 lesson: keep scalar
    int lane = tid & 63;
    int g = lane >> 4, i = lane & 15;
    if (BNPREV) {
        if (tid < 32) {
            float s = 0.f;
            #pragma unroll
            for (int r = 0; r < NREP; r++) s += statsPrev[r * 32 + tid];
            ssum[tid] = s;
        }
        __syncthreads();
        if (tid < 16) {
            float m = ssum[tid] * invN;
            float var = ssum[16 + tid] * invN - m * m;
            float sc = gPrev[tid] * rsqrtf(var + 1e-5f);
            scsh[tid] = sc;
            scsh[16 + tid] = bePrev[tid] - m * sc;
        }
        __syncthreads();
    }
    float scC = BNPREV ? scsh[i] : 1.f;
    float shC = BNPREV ? scsh[16 + i] : 0.f;
    int base = blockIdx.x * 16;

    const f32x4 zero4 = {0.f, 0.f, 0.f, 0.f};
    short8 ones;
    #pragma unroll
    for (int j = 0; j < 8; j++) ones[j] = (short)0x3F80;

    int st4[4], dg4[4];
    #pragma unroll
    for (int q = 0; q < 4; q++) {
        int node = base + w * 4 + q;
        bool v = node < N;
        st4[q] = v ? offs[node] : 0;
        dg4[q] = v ? cnt[node] : 0;
    }
    int mx = max(max(dg4[0], dg4[1]), max(dg4[2], dg4[3]));

    if (mx <= 32) {
        unsigned int aw[4][8], hw[4][8];
        #pragma unroll
        for (int q = 0; q < 4; q++) {
            #pragma unroll
            for (int j = 0; j < 8; j++) {
                int sl = 8 * g + j;
                bool ok = sl < dg4[q];
                size_t slc = ok ? (size_t)(st4[q] + sl) : 0;
                int src = srcSl[slc];
                unsigned int a = aP[slc * 16 + i];
                unsigned int h = hP[(size_t)src * 16 + i];
                aw[q][j] = ok ? a : 0u;
                hw[q][j] = ok ? h : 0u;
            }
        }
        #pragma unroll
        for (int q = 0; q < 4; q++) {
            short8 ah, al, hh, hl;
            #pragma unroll
            for (int j = 0; j < 8; j++) {
                ah[j] = (short)(aw[q][j] & 0xffffu);
                al[j] = (short)(aw[q][j] >> 16);
                hh[j] = (short)(hw[q][j] & 0xffffu);
                hl[j] = (short)(hw[q][j] >> 16);
            }
            f32x4 accM  = MFMA16(ah, hh, zero4);
            f32x4 accC  = MFMA16(ah, hl, zero4);
            accC        = MFMA16(al, hh, accC);
            f32x4 accSa = MFMA16(ah, ones, zero4);
            accSa       = MFMA16(al, ones, accSa);
            f32x4 accSh = MFMA16(ones, hh, zero4);
            accSh       = MFMA16(ones, hl, accSh);

            int node = base + w * 4 + q;
            int nvalid = node < N;
            int nl = w * 4 + q;
            float v0 = scC * (accM[0] + accC[0]) + shC * accSa[0];
            float v1 = scC * (accM[1] + accC[1]) + shC * accSa[1];
            float v2 = scC * (accM[2] + accC[2]) + shC * accSa[2];
            float v3 = scC * (accM[3] + accC[3]) + shC * accSa[3];
            unsigned short h0 = f2bf(v0), h1 = f2bf(v1), h2 = f2bf(v2), h3 = f2bf(v3);
            unsigned short l0 = f2bf(v0 - bf2f(h0)), l1 = f2bf(v1 - bf2f(h1));
            unsigned short l2 = f2bf(v2 - bf2f(h2)), l3 = f2bf(v3 - bf2f(h3));
            *(unsigned int*)&Bl[0][nl][i*18 + 4*g]     = (unsigned int)h0 | ((unsigned int)h1 << 16);
            *(unsigned int*)&Bl[0][nl][i*18 + 4*g + 2] = (unsigned int)h2 | ((unsigned int)h3 << 16);
            *(unsigned int*)&Bl[1][nl][i*18 + 4*g]     = (unsigned int)l0 | ((unsigned int)l1 << 16);
            *(unsigned int*)&Bl[1][nl][i*18 + 4*g + 2] = (unsigned int)l2 | ((unsigned int)l3 << 16);
            if (g == 0) {
                float v = scC * accSh[0] + shC * (float)dg4[q];
                unsigned short hh16 = f2bf(v);
                Bl[0][nl][i*18 + 16] = hh16;
                Bl[1][nl][i*18 + 16] = f2bf(v - bf2f(hh16));
            } else if (g == 1) {
                float hn = unpack2(hP[(size_t)(nvalid ? node : 0) * 16 + i]);
                float v = scC * hn + shC;
                unsigned short hh17 = f2bf(v);
                Bl[0][nl][i*18 + 17] = hh17;
                Bl[1][nl][i*18 + 17] = f2bf(v - bf2f(hh17));
            }
        }
    } else {
        for (int q = 0; q < 4; q++) {
            int node = base + w * 4 + q;
            int nvalid = node < N;
            int start = st4[q], deg = dg4[q];
            f32x4 accM  = zero4;
            f32x4 accC  = zero4;
            f32x4 accSa = zero4;
            f32x4 accSh = zero4;
            int nch = (deg + 31) >> 5;
            for (int ch = 0; ch < nch; ch++) {
                unsigned int aw[8], hw[8];
                #pragma unroll
                for (int j = 0; j < 8; j++) {
                    int sl = ch * 32 + 8 * g + j;
                    bool ok = sl < deg;
                    size_t slc = ok ? (size_t)(start + sl) : 0;
                    unsigned int a = aP[slc * 16 + i];
                    int src = srcSl[slc];
                    unsigned int h = hP[(size_t)src * 16 + i];
                    aw[j] = ok ? a : 0u;
                    hw[j] = ok ? h : 0u;
                }
                short8 ah, al, hh, hl;
                #pragma unroll
                for (int j = 0; j < 8; j++) {
                    ah[j] = (short)(aw[j] & 0xffffu);
                    al[j] = (short)(aw[j] >> 16);
                    hh[j] = (short)(hw[j] & 0xffffu);
                    hl[j] = (short)(hw[j] >> 16);
                }
                accM  = MFMA16(ah, hh, accM);
                accC  = MFMA16(ah, hl, accC);
                accC  = MFMA16(al, hh, accC);
                accSa = MFMA16(ah, ones, accSa);
                accSa = MFMA16(al, ones, accSa);
                accSh = MFMA16(ones, hh, accSh);
                accSh = MFMA16(ones, hl, accSh);
            }
            int nl = w * 4 + q;
            float v0 = scC * (accM[0] + accC[0]) + shC * accSa[0];
            float v1 = scC * (accM[1] + accC[1]) + shC * accSa[1];
            float v2 = scC * (accM[2] + accC[2]) + shC * accSa[2];
            float v3 = scC * (accM[3] + accC[3]) + shC * accSa[3];
            unsigned short h0 = f2bf(v0), h1 = f2bf(v1), h2 = f2bf(v2), h3 = f2bf(v3);
            unsigned short l0 = f2bf(v0 - bf2f(h0)), l1 = f2bf(v1 - bf2f(h1));
            unsigned short l2 = f2bf(v2 - bf2f(h2)), l3 = f2bf(v3 - bf2f(h3));
            *(unsigned int*)&Bl[0][nl][i*18 + 4*g]     = (unsigned int)h0 | ((unsigned int)h1 << 16);
            *(unsigned int*)&Bl[0][nl][i*18 + 4*g + 2] = (unsigned int)h2 | ((unsigned int)h3 << 16);
            *(unsigned int*)&Bl[1][nl][i*18 + 4*g]     = (unsigned int)l0 | ((unsigned int)l1 << 16);
            *(unsigned int*)&Bl[1][nl][i*18 + 4*g + 2] = (unsigned int)l2 | ((unsigned int)l3 << 16);
            if (g == 0) {
                float v = scC * accSh[0] + shC * (float)deg;
                unsigned short hh16 = f2bf(v);
                Bl[0][nl][i*18 + 16] = hh16;
                Bl[1][nl][i*18 + 16] = f2bf(v - bf2f(hh16));
            } else if (g == 1) {
                float hn = unpack2(hP[(size_t)(nvalid ? node : 0) * 16 + i]);
                float v = scC * hn + shC;
                unsigned short hh17 = f2bf(v);
                Bl[0][nl][i*18 + 17] = hh17;
                Bl[1][nl][i*18 + 17] = f2bf(v - bf2f(hh17));
            }
        }
    }
    __syncthreads();

    if (w != 0) return;

    float cbv = cb[i];
    f32x4 acc0 = {cbv, cbv, cbv, cbv};
    f32x4 acc1 = zero4;
    f32x4 acc2 = zero4;
    const short8* wf = (const short8*)wfragL;
    #pragma unroll
    for (int t = 0; t < 9; t++) {
        short8 whi = wf[(t*2+0)*64 + lane];
        short8 wlo = wf[(t*2+1)*64 + lane];
        short8 ahi = *(const short8*)&Bl[0][i][32*t + 8*g];
        short8 alo = *(const short8*)&Bl[1][i][32*t + 8*g];
        acc0 = MFMA16(ahi, whi, acc0);
        acc1 = MFMA16(ahi, wlo, acc1);
        acc2 = MFMA16(alo, whi, acc2);
    }

    float s1 = 0.f, s2 = 0.f;
    #pragma unroll
    for (int rr = 0; rr < 4; rr++) {
        int n2 = base + 4*g + rr;
        float v = fmaxf(acc0[rr] + acc1[rr] + acc2[rr], 0.f);
        if (n2 < N) {
            houtP[(size_t)n2 * 16 + i] = pack2(v);
            s1 += v; s2 += v * v;
        }
    }
    s1 += __shfl_xor(s1, 16); s1 += __shfl_xor(s1, 32);
    s2 += __shfl_xor(s2, 16); s2 += __shfl_xor(s2, 32);
    if (lane < 16) {
        float* repl = statsCur + (blockIdx.x & (NREP - 1)) * 32;
        atomicAdd(&repl[i], s1);
        atomicAdd(&repl[16 + i], s2);
    }
}

// ---------------- mu / logvar / reparameterize (BN stats from replicas) ----
__global__ __launch_bounds__(256) void k_z(
    const unsigned int* __restrict__ hP, const float* __restrict__ stats4,
    const float* __restrict__ g4, const float* __restrict__ be4,
    const float* __restrict__ mu_w, const float* __restrict__ mu_b,
    const float* __restrict__ lv_w, const float* __restrict__ lv_b,
    const float* __restrict__ eps, float* __restrict__ z, int N, float invN)
{
    __shared__ float scsh[32];
    __shared__ float ssum[32];
    int tid = threadIdx.x;
    if (tid < 32) {
        float s = 0.f;
        #pragma unroll
        for (int r = 0; r < NREP; r++) s += stats4[r * 32 + tid];
        ssum[tid] = s;
    }
    __syncthreads();
    if (tid < 16) {
        float m = ssum[tid] * invN;
        float var = ssum[16 + tid] * invN - m * m;
        float sc = g4[tid] * rsqrtf(var + 1e-5f);
        scsh[tid] = sc;
        scsh[16 + tid] = be4[tid] - m * sc;
    }
    __syncthreads();
    int t = blockIdx.x * 256 + tid;
    if (t >= N * 16) return;
    int n = t >> 4, o = t & 15;
    const uint4* hp4 = (const uint4*)(hP + (size_t)n * 16);
    uint4 u0 = hp4[0], u1 = hp4[1], u2 = hp4[2], u3 = hp4[3];
    unsigned int uu[16] = {u0.x,u0.y,u0.z,u0.w, u1.x,u1.y,u1.z,u1.w,
                           u2.x,u2.y,u2.z,u2.w, u3.x,u3.y,u3.z,u3.w};
    float mu = mu_b[o], lv = lv_b[o];
    #pragma unroll
    for (int j = 0; j < 16; j++) {
        float hv = unpack2(uu[j]) * scsh[j] + scsh[16 + j];
        mu += hv * mu_w[j * 16 + o];
        lv += hv * lv_w[j * 16 + o];
    }
    lv = fminf(lv, 10.f);
    z[t] = mu + eps[t] * expf(0.5f * lv);
}

// ---------------- MFMA decoder (R13-verified: 1 tile/wave, weights from L1) -------------
// R14/R15 lessons: 2-tile ILP at 144 VGPR loses a wave/SIMD (46->51us); capping at
// 128 VGPR via __launch_bounds__(256,4) spills to scratch (46->234us, FETCH 21->609MB).
// This 124-VGPR single-tile body is the measured local optimum. T=4 tiles/wave gives
// 3x block oversubscription (weights are L1-resident per tile; long T buys nothing).
#define REPACK() do { \
    float av[16]; \
    _Pragma("unroll") for (int mt = 0; mt < 4; mt++) { \
        _Pragma("unroll") for (int r = 0; r < 4; r++) av[mt*4 + r] = acc[mt][r]; } \
    _Pragma("unroll") for (int kt = 0; kt < 2; kt++) { \
        _Pragma("unroll") for (int j = 0; j < 8; j++) \
            a2[kt][j] = (short)f2bf(fmaxf(av[(2*kt + (j>>2))*4 + (j&3)], 0.f)); } \
} while (0)

#define DENSE(OFS, DB) do { \
    _Pragma("unroll") for (int mt = 0; mt < 4; mt++) acc[mt] = *(const f32x4*)((DB) + 16*mt + 4*g); \
    _Pragma("unroll") for (int mt = 0; mt < 4; mt++) acc[mt] = MFMA16(wf[((OFS) + mt*2)*64 + lane], a2[0], acc[mt]); \
    _Pragma("unroll") for (int mt = 0; mt < 4; mt++) acc[mt] = MFMA16(wf[((OFS) + mt*2 + 1)*64 + lane], a2[1], acc[mt]); \
    REPACK(); \
} while (0)

__global__ __launch_bounds__(256) void k_dec(
    const float* __restrict__ z, const int* __restrict__ ei,
    const unsigned short* __restrict__ wfrag,
    const float* __restrict__ db0, const float* __restrict__ db1,
    const float* __restrict__ db2, const float* __restrict__ db3,
    const float* __restrict__ db4,
    float* __restrict__ out, int E, int T, int totalTiles)
{
    int wid = blockIdx.x * 4 + (threadIdx.x >> 6);
    int lane = threadIdx.x & 63;
    int g = lane >> 4, c = lane & 15;
    int t0 = wid * T;
    if (t0 >= totalTiles) return;
    int t1 = min(t0 + T, totalTiles);

    const short8* wf = (const short8*)wfrag;

    int eiOfs = (g < 2) ? 0 : E;
    int zofs = (g & 1) * 8;

    int node = ei[eiOfs + min(t0 * 16 + c, E - 1)];
    f32x4 zv0 = *(const f32x4*)(z + (size_t)node * 16 + zofs);
    f32x4 zv1 = *(const f32x4*)(z + (size_t)node * 16 + zofs + 4);
    int node_n = 0;
    if (t0 + 1 < t1) node_n = ei[eiOfs + min((t0 + 1) * 16 + c, E - 1)];

    for (int t = t0; t < t1; ++t) {
        f32x4 zn0 = {0.f,0.f,0.f,0.f}, zn1 = {0.f,0.f,0.f,0.f};
        if (t + 1 < t1) {
            zn0 = *(const f32x4*)(z + (size_t)node_n * 16 + zofs);
            zn1 = *(const f32x4*)(z + (size_t)node_n * 16 + zofs + 4);
        }
        int node_nn = 0;
        if (t + 2 < t1) node_nn = ei[eiOfs + min((t + 2) * 16 + c, E - 1)];

        short8 af0;
        #pragma unroll
        for (int j = 0; j < 4; j++) {
            af0[j]     = (short)f2bf(zv0[j]);
            af0[4 + j] = (short)f2bf(zv1[j]);
        }
        f32x4 acc[4];
        short8 a2[2];
        #pragma unroll
        for (int mt = 0; mt < 4; mt++) acc[mt] = *(const f32x4*)(db0 + 16*mt + 4*g);
        #pragma unroll
        for (int mt = 0; mt < 4; mt++) acc[mt] = MFMA16(wf[mt*64 + lane], af0, acc[mt]);
        REPACK();

        DENSE(4,  db1);
        DENSE(12, db2);
        DENSE(20, db3);

        f32x4 o4;
        if (g < 2) o4 = *(const f32x4*)(db4 + 4*g);
        else { o4[0]=0.f; o4[1]=0.f; o4[2]=0.f; o4[3]=0.f; }
        o4 = MFMA16(wf[28*64 + lane], a2[0], o4);
        o4 = MFMA16(wf[29*64 + lane], a2[1], o4);

        int e = t * 16 + c;
        if (g < 2 && e < E) *(f32x4*)(out + (size_t)e * 8 + 4*g) = o4;

        zv0 = zn0; zv1 = zn1; node_n = node_nn;
    }
}

// ---------------- launch ----------------
extern "C" void kernel_launch(void* const* d_in, const int* in_sizes, int n_in,
                              void* d_out, int out_size, void* d_ws, size_t ws_size,
                              hipStream_t stream)
{
    const float* x   = (const float*)d_in[0];
    const int*   ei  = (const int*)d_in[1];
    const float* ea  = (const float*)d_in[2];
    const float* eps = (const float*)d_in[3];
    const float* w1  = (const float*)d_in[4];
    const float* b1  = (const float*)d_in[5];
    const float* w2  = (const float*)d_in[6];
    const float* b2  = (const float*)d_in[7];
    const float* root[4]; const float* cb[4]; const float* g[4]; const float* be[4];
    for (int l = 0; l < 4; l++) {
        root[l] = (const float*)d_in[8 + 4*l];
        cb[l]   = (const float*)d_in[9 + 4*l];
        g[l]    = (const float*)d_in[10 + 4*l];
        be[l]   = (const float*)d_in[11 + 4*l];
    }
    const float* mu_w = (const float*)d_in[24];
    const float* mu_b = (const float*)d_in[25];
    const float* lv_w = (const float*)d_in[26];
    const float* lv_b = (const float*)d_in[27];
    const float* dw[5]; const float* db[5];
    for (int i = 0; i < 5; i++) {
        dw[i] = (const float*)d_in[28 + 2*i];
        db[i] = (const float*)d_in[29 + 2*i];
    }
    float* out = (float*)d_out;

    int N = in_sizes[0] / 16;
    int E = in_sizes[2] / 8;
    float invN = 1.0f / N;

    // ---- workspace layout ----
    int*   cnt      = (int*)d_ws;                       // N
    float* statsRep = (float*)(cnt + N);                // 4 x NREP x 32
    int*   offs     = (int*)(statsRep + 4 * NREP * 32); // N
    int*   bsum     = offs + N;                         // 256
    int*   slotOf   = bsum + 256;                       // E (rank, then slot)
    int*   srcSl    = slotOf + E;                       // E
    unsigned int* aP  = (unsigned int*)(srcSl + E);     // E*16 (packed)
    unsigned int* xP  = aP + (size_t)E * 16;            // N*16 (packed)
    unsigned int* hA  = xP + (size_t)N * 16;            // N*16 (packed)
    unsigned int* hB  = hA + (size_t)N * 16;            // N*16 (packed)
    float* zbuf     = (float*)(hB + (size_t)N * 16);    // N*16
    unsigned short* wfrag  = (unsigned short*)(zbuf + (size_t)N * 16); // 15360
    unsigned short* wfrag2 = wfrag + 15360;             // 36864

    int nbScan = (N + 255) / 256;

    (void)hipMemsetAsync(cnt, 0, ((size_t)N + 4 * NREP * 32) * sizeof(int), stream);

    k_wpreps<<<17, 256, 0, stream>>>(dw[0], dw[1], dw[2], dw[3], dw[4], wfrag,
                                     w2, b2, root[0], root[1], root[2], root[3], wfrag2);
    k_pack<<<(N * 16 + 255) / 256, 256, 0, stream>>>(x, xP, N * 16);

    k_fillR<<<(E + 255) / 256, 256, 0, stream>>>(ei, cnt, slotOf, E);
    k_scanA<<<nbScan, 256, 0, stream>>>(cnt, offs, bsum, N);
    k_scanB<<<1, 256, 0, stream>>>(bsum, nbScan);
    k_scanC<<<nbScan, 256, 0, stream>>>(offs, bsum, N);
    k_scatter<<<(E + 255) / 256, 256, 0, stream>>>(ei, offs, slotOf, srcSl, E);

    k_a<<<(E + 255) / 256, 256, 0, stream>>>(ea, w1, b1, slotOf, aP, E);

    int nbF = (N + 15) / 16;
    float* sr0 = statsRep + 0 * NREP * 32;
    float* sr1 = statsRep + 1 * NREP * 32;
    float* sr2 = statsRep + 2 * NREP * 32;
    float* sr3 = statsRep + 3 * NREP * 32;

    k_fuse3<0><<<nbF, 256, 0, stream>>>(xP, nullptr, nullptr, nullptr,
                                        offs, cnt, srcSl, aP,
                                        wfrag2 + 0 * 9216, cb[0], hA, sr0, N, invN);
    k_fuse3<1><<<nbF, 256, 0, stream>>>(hA, sr0, g[0], be[0],
                                        offs, cnt, srcSl, aP,
                                        wfrag2 + 1 * 9216, cb[1], hB, sr1, N, invN);
    k_fuse3<1><<<nbF, 256, 0, stream>>>(hB, sr1, g[1], be[1],
                                        offs, cnt, srcSl, aP,
                                        wfrag2 + 2 * 9216, cb[2], hA, sr2, N, invN);
    k_fuse3<1><<<nbF, 256, 0, stream>>>(hA, sr2, g[2], be[2],
                                        offs, cnt, srcSl, aP,
                                        wfrag2 + 3 * 9216, cb[3], hB, sr3, N, invN);

    k_z<<<(N * 16 + 255) / 256, 256, 0, stream>>>(hB, sr3, g[3], be[3],
                                                  mu_w, mu_b, lv_w, lv_b, eps, zbuf, N, invN);

    // decoder: R13 body; T=4 -> ~3x block oversubscription for latency hiding
    int totalTiles = (E + 15) >> 4;
    int T = 4;
    int wavesUsed = (totalTiles + T - 1) / T;
    int blocks = (wavesUsed + 3) / 4;
    k_dec<<<blocks, 256, 0, stream>>>(zbuf, ei, wfrag,
        db[0], db[1], db[2], db[3], db[4], out, E, T, totalTiles);
}

// Round 17
// 267.503 us; speedup vs baseline: 1.7327x; 1.0231x over previous
//
#include <hip/hip_runtime.h>
#include <hip/hip_bf16.h>
#include <math.h>

using short8 = __attribute__((ext_vector_type(8))) short;
using f32x4  = __attribute__((ext_vector_type(4))) float;

#define NREP 32   // BN-stats replica buckets (contention /32)

__device__ __forceinline__ unsigned short f2bf(float x) {
    return __builtin_bit_cast(unsigned short, __float2bfloat16(x));
}
__device__ __forceinline__ float bf2f(unsigned short u) {
    unsigned int x = ((unsigned int)u) << 16;
    return __builtin_bit_cast(float, x);
}
// packed hi/lo bf16 in one u32: bits[15:0]=hi (main), bits[31:16]=lo (residual)
__device__ __forceinline__ unsigned int pack2(float v) {
    unsigned short h = f2bf(v);
    unsigned short l = f2bf(v - bf2f(h));
    return (unsigned int)h | ((unsigned int)l << 16);
}
__device__ __forceinline__ float unpack2(unsigned int u) {
    return bf2f((unsigned short)(u & 0xffff)) + bf2f((unsigned short)(u >> 16));
}

#define MFMA16(A,B,C) __builtin_amdgcn_mfma_f32_16x16x32_bf16((A),(B),(C),0,0,0)

// ---------------- CSR build (rank-based: ONE atomic pass) ----------------
__global__ __launch_bounds__(256) void k_fillR(const int* __restrict__ ei, int* __restrict__ cnt,
                                               int* __restrict__ rank, int E) {
    int e = blockIdx.x * blockDim.x + threadIdx.x;
    if (e < E) rank[e] = atomicAdd(&cnt[ei[E + e]], 1);
}

__global__ __launch_bounds__(256) void k_scanA(const int* __restrict__ cnt, int* __restrict__ offs,
                                               int* __restrict__ bsum, int N) {
    __shared__ int s[256];
    int i = blockIdx.x * 256 + threadIdx.x;
    int v = (i < N) ? cnt[i] : 0;
    s[threadIdx.x] = v;
    __syncthreads();
    #pragma unroll
    for (int d = 1; d < 256; d <<= 1) {
        int t = (threadIdx.x >= d) ? s[threadIdx.x - d] : 0;
        __syncthreads();
        s[threadIdx.x] += t;
        __syncthreads();
    }
    if (i < N) offs[i] = s[threadIdx.x] - v;
    if (threadIdx.x == 255) bsum[blockIdx.x] = s[255];
}

__global__ __launch_bounds__(256) void k_scanB(int* __restrict__ bsum, int nb) {
    __shared__ int s[256];
    int v = (threadIdx.x < nb) ? bsum[threadIdx.x] : 0;
    s[threadIdx.x] = v;
    __syncthreads();
    #pragma unroll
    for (int d = 1; d < 256; d <<= 1) {
        int t = (threadIdx.x >= d) ? s[threadIdx.x - d] : 0;
        __syncthreads();
        s[threadIdx.x] += t;
        __syncthreads();
    }
    if (threadIdx.x < nb) bsum[threadIdx.x] = s[threadIdx.x] - v;
}

__global__ __launch_bounds__(256) void k_scanC(int* __restrict__ offs, const int* __restrict__ bsum, int N) {
    int i = blockIdx.x * 256 + threadIdx.x;
    if (i < N) offs[i] += bsum[blockIdx.x];
}

__global__ __launch_bounds__(256) void k_scatter(const int* __restrict__ ei, const int* __restrict__ offs,
                                                 int* __restrict__ slotOf, int* __restrict__ srcSl, int E) {
    int e = blockIdx.x * blockDim.x + threadIdx.x;
    if (e < E) {
        int d = ei[E + e];
        int slot = offs[d] + slotOf[e];
        slotOf[e] = slot;
        srcSl[slot] = ei[e];
    }
}

// ---------------- pack x into hi/lo format ----------------
__global__ __launch_bounds__(256) void k_pack(const float* __restrict__ x,
                                              unsigned int* __restrict__ xP, int n) {
    int t = blockIdx.x * 256 + threadIdx.x;
    if (t < n) xP[t] = pack2(x[t]);
}

// ---------------- edge MLP a = relu(ea@w1+b1), packed hi/lo, slot order ----------------
__global__ __launch_bounds__(256) void k_a(
    const float* __restrict__ ea, const float* __restrict__ w1,
    const float* __restrict__ b1, const int* __restrict__ slotOf,
    unsigned int* __restrict__ aP, int E)
{
    int e = blockIdx.x * 256 + threadIdx.x;
    if (e >= E) return;
    const float4* p = (const float4*)(ea + (size_t)e * 8);
    float4 v0 = p[0], v1 = p[1];
    float eav[8] = {v0.x, v0.y, v0.z, v0.w, v1.x, v1.y, v1.z, v1.w};
    float a[16];
    #pragma unroll
    for (int k = 0; k < 16; k++) a[k] = b1[k];
    #pragma unroll
    for (int q = 0; q < 8; q++) {
        float ev = eav[q];
        #pragma unroll
        for (int k = 0; k < 16; k++) a[k] += ev * w1[q * 16 + k];
    }
    unsigned int pk[16];
    #pragma unroll
    for (int k = 0; k < 16; k++) pk[k] = pack2(fmaxf(a[k], 0.f));
    int slot = slotOf[e];
    uint4* o = (uint4*)(aP + (size_t)slot * 16);
    o[0] = make_uint4(pk[0], pk[1], pk[2], pk[3]);
    o[1] = make_uint4(pk[4], pk[5], pk[6], pk[7]);
    o[2] = make_uint4(pk[8], pk[9], pk[10], pk[11]);
    o[3] = make_uint4(pk[12], pk[13], pk[14], pk[15]);
}

// ---------------- combined weight prep: decoder frags (t<1920) + W2cat (t<4224) ----------
__global__ void k_wpreps(const float* __restrict__ dw0, const float* __restrict__ dw1,
                         const float* __restrict__ dw2, const float* __restrict__ dw3,
                         const float* __restrict__ dw4, unsigned short* __restrict__ wfrag,
                         const float* __restrict__ w2, const float* __restrict__ b2,
                         const float* __restrict__ r0, const float* __restrict__ r1,
                         const float* __restrict__ r2, const float* __restrict__ r3,
                         unsigned short* __restrict__ wf2)
{
    int tid = blockIdx.x * 256 + threadIdx.x;
    if (tid < 1920) {
        int f = tid >> 6, lane = tid & 63, g = lane >> 4, c = lane & 15;
        float v[8];
        if (f < 4) {
            int mt = f;
            #pragma unroll
            for (int j = 0; j < 8; j++) v[j] = dw0[(8*g + j) * 64 + 16*mt + c];
        } else if (f < 28) {
            int fl = f - 4;
            const float* W = (fl >> 3) == 0 ? dw1 : ((fl >> 3) == 1 ? dw2 : dw3);
            int mt = (fl & 7) >> 1, kt = fl & 1;
            #pragma unroll
            for (int j = 0; j < 8; j++) {
                int in = 16*(2*kt + (j>>2)) + 4*g + (j&3);
                v[j] = W[in * 64 + 16*mt + c];
            }
        } else {
            int kt = f - 28;
            #pragma unroll
            for (int j = 0; j < 8; j++) {
                int in = 16*(2*kt + (j>>2)) + 4*g + (j&3);
                v[j] = (c < 8) ? dw4[in * 8 + c] : 0.f;
            }
        }
        unsigned short* o = wfrag + (size_t)tid * 8;
        #pragma unroll
        for (int j = 0; j < 8; j++) o[j] = f2bf(v[j]);
    } else if (tid < 1920 + 2304) {
        int t2 = tid - 1920;
        int l = t2 / 576, rem = t2 % 576;
        int t = rem / 64, lane = rem % 64;
        int g = lane >> 4, o = lane & 15;
        const float* roots[4] = {r0, r1, r2, r3};
        unsigned short hi8[8], lo8[8];
        #pragma unroll
        for (int j = 0; j < 8; j++) {
            int kp = 32 * t + 8 * g + j;
            int i = kp / 18, k = kp % 18;
            float v;
            if (k < 16)      v = w2[k * 256 + i * 16 + o];
            else if (k == 16) v = b2[i * 16 + o];
            else              v = roots[l][i * 16 + o];
            unsigned short h = f2bf(v);
            hi8[j] = h;
            lo8[j] = f2bf(v - bf2f(h));
        }
        unsigned short* oh = wf2 + (size_t)l * 9216 + (t * 2 + 0) * 512 + lane * 8;
        unsigned short* ol = wf2 + (size_t)l * 9216 + (t * 2 + 1) * 512 + lane * 8;
        #pragma unroll
        for (int j = 0; j < 8; j++) { oh[j] = hi8[j]; ol[j] = lo8[j]; }
    }
}

// ---------------- fused conv layer v7: replicated BN-stats (verified R13) ------------
template<int BNPREV>
__global__ __launch_bounds__(256) void k_fuse3(
    const unsigned int* __restrict__ hP, const float* __restrict__ statsPrev,
    const float* __restrict__ gPrev, const float* __restrict__ bePrev,
    const int* __restrict__ offs, const int* __restrict__ cnt,
    const int* __restrict__ srcSl, const unsigned int* __restrict__ aP,
    const unsigned short* __restrict__ wfragL, const float* __restrict__ cb,
    unsigned int* __restrict__ houtP, float* __restrict__ statsCur,
    int N, float invN)
{
    __shared__ unsigned short Bl[2][16][296];
    __shared__ float scsh[32];
    __shared__ float ssum[32];
    int tid = threadIdx.x;
    int w = __builtin_amdgcn_readfirstlane(tid >> 6);   // R4 lesson: keep scalar
    int lane = tid & 63;
    int g = lane >> 4, i = lane & 15;
    if (BNPREV) {
        if (tid < 32) {
            float s = 0.f;
            #pragma unroll
            for (int r = 0; r < NREP; r++) s += statsPrev[r * 32 + tid];
            ssum[tid] = s;
        }
        __syncthreads();
        if (tid < 16) {
            float m = ssum[tid] * invN;
            float var = ssum[16 + tid] * invN - m * m;
            float sc = gPrev[tid] * rsqrtf(var + 1e-5f);
            scsh[tid] = sc;
            scsh[16 + tid] = bePrev[tid] - m * sc;
        }
        __syncthreads();
    }
    float scC = BNPREV ? scsh[i] : 1.f;
    float shC = BNPREV ? scsh[16 + i] : 0.f;
    int base = blockIdx.x * 16;

    const f32x4 zero4 = {0.f, 0.f, 0.f, 0.f};
    short8 ones;
    #pragma unroll
    for (int j = 0; j < 8; j++) ones[j] = (short)0x3F80;

    int st4[4], dg4[4];
    #pragma unroll
    for (int q = 0; q < 4; q++) {
        int node = base + w * 4 + q;
        bool v = node < N;
        st4[q] = v ? offs[node] : 0;
        dg4[q] = v ? cnt[node] : 0;
    }
    int mx = max(max(dg4[0], dg4[1]), max(dg4[2], dg4[3]));

    if (mx <= 32) {
        unsigned int aw[4][8], hw[4][8];
        #pragma unroll
        for (int q = 0; q < 4; q++) {
            #pragma unroll
            for (int j = 0; j < 8; j++) {
                int sl = 8 * g + j;
                bool ok = sl < dg4[q];
                size_t slc = ok ? (size_t)(st4[q] + sl) : 0;
                int src = srcSl[slc];
                unsigned int a = aP[slc * 16 + i];
                unsigned int h = hP[(size_t)src * 16 + i];
                aw[q][j] = ok ? a : 0u;
                hw[q][j] = ok ? h : 0u;
            }
        }
        #pragma unroll
        for (int q = 0; q < 4; q++) {
            short8 ah, al, hh, hl;
            #pragma unroll
            for (int j = 0; j < 8; j++) {
                ah[j] = (short)(aw[q][j] & 0xffffu);
                al[j] = (short)(aw[q][j] >> 16);
                hh[j] = (short)(hw[q][j] & 0xffffu);
                hl[j] = (short)(hw[q][j] >> 16);
            }
            f32x4 accM  = MFMA16(ah, hh, zero4);
            f32x4 accC  = MFMA16(ah, hl, zero4);
            accC        = MFMA16(al, hh, accC);
            f32x4 accSa = MFMA16(ah, ones, zero4);
            accSa       = MFMA16(al, ones, accSa);
            f32x4 accSh = MFMA16(ones, hh, zero4);
            accSh       = MFMA16(ones, hl, accSh);

            int node = base + w * 4 + q;
            int nvalid = node < N;
            int nl = w * 4 + q;
            float v0 = scC * (accM[0] + accC[0]) + shC * accSa[0];
            float v1 = scC * (accM[1] + accC[1]) + shC * accSa[1];
            float v2 = scC * (accM[2] + accC[2]) + shC * accSa[2];
            float v3 = scC * (accM[3] + accC[3]) + shC * accSa[3];
            unsigned short h0 = f2bf(v0), h1 = f2bf(v1), h2 = f2bf(v2), h3 = f2bf(v3);
            unsigned short l0 = f2bf(v0 - bf2f(h0)), l1 = f2bf(v1 - bf2f(h1));
            unsigned short l2 = f2bf(v2 - bf2f(h2)), l3 = f2bf(v3 - bf2f(h3));
            *(unsigned int*)&Bl[0][nl][i*18 + 4*g]     = (unsigned int)h0 | ((unsigned int)h1 << 16);
            *(unsigned int*)&Bl[0][nl][i*18 + 4*g + 2] = (unsigned int)h2 | ((unsigned int)h3 << 16);
            *(unsigned int*)&Bl[1][nl][i*18 + 4*g]     = (unsigned int)l0 | ((unsigned int)l1 << 16);
            *(unsigned int*)&Bl[1][nl][i*18 + 4*g + 2] = (unsigned int)l2 | ((unsigned int)l3 << 16);
            if (g == 0) {
                float v = scC * accSh[0] + shC * (float)dg4[q];
                unsigned short hh16 = f2bf(v);
                Bl[0][nl][i*18 + 16] = hh16;
                Bl[1][nl][i*18 + 16] = f2bf(v - bf2f(hh16));
            } else if (g == 1) {
                float hn = unpack2(hP[(size_t)(nvalid ? node : 0) * 16 + i]);
                float v = scC * hn + shC;
                unsigned short hh17 = f2bf(v);
                Bl[0][nl][i*18 + 17] = hh17;
                Bl[1][nl][i*18 + 17] = f2bf(v - bf2f(hh17));
            }
        }
    } else {
        for (int q = 0; q < 4; q++) {
            int node = base + w * 4 + q;
            int nvalid = node < N;
            int start = st4[q], deg = dg4[q];
            f32x4 accM  = zero4;
            f32x4 accC  = zero4;
            f32x4 accSa = zero4;
            f32x4 accSh = zero4;
            int nch = (deg + 31) >> 5;
            for (int ch = 0; ch < nch; ch++) {
                unsigned int aw[8], hw[8];
                #pragma unroll
                for (int j = 0; j < 8; j++) {
                    int sl = ch * 32 + 8 * g + j;
                    bool ok = sl < deg;
                    size_t slc = ok ? (size_t)(start + sl) : 0;
                    unsigned int a = aP[slc * 16 + i];
                    int src = srcSl[slc];
                    unsigned int h = hP[(size_t)src * 16 + i];
                    aw[j] = ok ? a : 0u;
                    hw[j] = ok ? h : 0u;
                }
                short8 ah, al, hh, hl;
                #pragma unroll
                for (int j = 0; j < 8; j++) {
                    ah[j] = (short)(aw[j] & 0xffffu);
                    al[j] = (short)(aw[j] >> 16);
                    hh[j] = (short)(hw[j] & 0xffffu);
                    hl[j] = (short)(hw[j] >> 16);
                }
                accM  = MFMA16(ah, hh, accM);
                accC  = MFMA16(ah, hl, accC);
                accC  = MFMA16(al, hh, accC);
                accSa = MFMA16(ah, ones, accSa);
                accSa = MFMA16(al, ones, accSa);
                accSh = MFMA16(ones, hh, accSh);
                accSh = MFMA16(ones, hl, accSh);
            }
            int nl = w * 4 + q;
            float v0 = scC * (accM[0] + accC[0]) + shC * accSa[0];
            float v1 = scC * (accM[1] + accC[1]) + shC * accSa[1];
            float v2 = scC * (accM[2] + accC[2]) + shC * accSa[2];
            float v3 = scC * (accM[3] + accC[3]) + shC * accSa[3];
            unsigned short h0 = f2bf(v0), h1 = f2bf(v1), h2 = f2bf(v2), h3 = f2bf(v3);
            unsigned short l0 = f2bf(v0 - bf2f(h0)), l1 = f2bf(v1 - bf2f(h1));
            unsigned short l2 = f2bf(v2 - bf2f(h2)), l3 = f2bf(v3 - bf2f(h3));
            *(unsigned int*)&Bl[0][nl][i*18 + 4*g]     = (unsigned int)h0 | ((unsigned int)h1 << 16);
            *(unsigned int*)&Bl[0][nl][i*18 + 4*g + 2] = (unsigned int)h2 | ((unsigned int)h3 << 16);
            *(unsigned int*)&Bl[1][nl][i*18 + 4*g]     = (unsigned int)l0 | ((unsigned int)l1 << 16);
            *(unsigned int*)&Bl[1][nl][i*18 + 4*g + 2] = (unsigned int)l2 | ((unsigned int)l3 << 16);
            if (g == 0) {
                float v = scC * accSh[0] + shC * (float)deg;
                unsigned short hh16 = f2bf(v);
                Bl[0][nl][i*18 + 16] = hh16;
                Bl[1][nl][i*18 + 16] = f2bf(v - bf2f(hh16));
            } else if (g == 1) {
                float hn = unpack2(hP[(size_t)(nvalid ? node : 0) * 16 + i]);
                float v = scC * hn + shC;
                unsigned short hh17 = f2bf(v);
                Bl[0][nl][i*18 + 17] = hh17;
                Bl[1][nl][i*18 + 17] = f2bf(v - bf2f(hh17));
            }
        }
    }
    __syncthreads();

    if (w != 0) return;

    float cbv = cb[i];
    f32x4 acc0 = {cbv, cbv, cbv, cbv};
    f32x4 acc1 = zero4;
    f32x4 acc2 = zero4;
    const short8* wf = (const short8*)wfragL;
    #pragma unroll
    for (int t = 0; t < 9; t++) {
        short8 whi = wf[(t*2+0)*64 + lane];
        short8 wlo = wf[(t*2+1)*64 + lane];
        short8 ahi = *(const short8*)&Bl[0][i][32*t + 8*g];
        short8 alo = *(const short8*)&Bl[1][i][32*t + 8*g];
        acc0 = MFMA16(ahi, whi, acc0);
        acc1 = MFMA16(ahi, wlo, acc1);
        acc2 = MFMA16(alo, whi, acc2);
    }

    float s1 = 0.f, s2 = 0.f;
    #pragma unroll
    for (int rr = 0; rr < 4; rr++) {
        int n2 = base + 4*g + rr;
        float v = fmaxf(acc0[rr] + acc1[rr] + acc2[rr], 0.f);
        if (n2 < N) {
            houtP[(size_t)n2 * 16 + i] = pack2(v);
            s1 += v; s2 += v * v;
        }
    }
    s1 += __shfl_xor(s1, 16); s1 += __shfl_xor(s1, 32);
    s2 += __shfl_xor(s2, 16); s2 += __shfl_xor(s2, 32);
    if (lane < 16) {
        float* repl = statsCur + (blockIdx.x & (NREP - 1)) * 32;
        atomicAdd(&repl[i], s1);
        atomicAdd(&repl[16 + i], s2);
    }
}

// ---------------- mu / logvar / reparameterize (BN stats from replicas) ----
__global__ __launch_bounds__(256) void k_z(
    const unsigned int* __restrict__ hP, const float* __restrict__ stats4,
    const float* __restrict__ g4, const float* __restrict__ be4,
    const float* __restrict__ mu_w, const float* __restrict__ mu_b,
    const float* __restrict__ lv_w, const float* __restrict__ lv_b,
    const float* __restrict__ eps, float* __restrict__ z, int N, float invN)
{
    __shared__ float scsh[32];
    __shared__ float ssum[32];
    int tid = threadIdx.x;
    if (tid < 32) {
        float s = 0.f;
        #pragma unroll
        for (int r = 0; r < NREP; r++) s += stats4[r * 32 + tid];
        ssum[tid] = s;
    }
    __syncthreads();
    if (tid < 16) {
        float m = ssum[tid] * invN;
        float var = ssum[16 + tid] * invN - m * m;
        float sc = g4[tid] * rsqrtf(var + 1e-5f);
        scsh[tid] = sc;
        scsh[16 + tid] = be4[tid] - m * sc;
    }
    __syncthreads();
    int t = blockIdx.x * 256 + tid;
    if (t >= N * 16) return;
    int n = t >> 4, o = t & 15;
    const uint4* hp4 = (const uint4*)(hP + (size_t)n * 16);
    uint4 u0 = hp4[0], u1 = hp4[1], u2 = hp4[2], u3 = hp4[3];
    unsigned int uu[16] = {u0.x,u0.y,u0.z,u0.w, u1.x,u1.y,u1.z,u1.w,
                           u2.x,u2.y,u2.z,u2.w, u3.x,u3.y,u3.z,u3.w};
    float mu = mu_b[o], lv = lv_b[o];
    #pragma unroll
    for (int j = 0; j < 16; j++) {
        float hv = unpack2(uu[j]) * scsh[j] + scsh[16 + j];
        mu += hv * mu_w[j * 16 + o];
        lv += hv * lv_w[j * 16 + o];
    }
    lv = fminf(lv, 10.f);
    z[t] = mu + eps[t] * expf(0.5f * lv);
}

// ---------------- MFMA decoder (R13-verified: 1 tile/wave, T~13, weights from L1) -------
// Bracketing evidence: T=4 re-pays wave prologue (52us, R16); 2-tile ILP at 144 VGPR
// loses a wave/SIMD (51us, R14); 128-VGPR cap spills to scratch (234us, R15).
// This exact config measured 46us (R13) — local optimum.
#define REPACK() do { \
    float av[16]; \
    _Pragma("unroll") for (int mt = 0; mt < 4; mt++) { \
        _Pragma("unroll") for (int r = 0; r < 4; r++) av[mt*4 + r] = acc[mt][r]; } \
    _Pragma("unroll") for (int kt = 0; kt < 2; kt++) { \
        _Pragma("unroll") for (int j = 0; j < 8; j++) \
            a2[kt][j] = (short)f2bf(fmaxf(av[(2*kt + (j>>2))*4 + (j&3)], 0.f)); } \
} while (0)

#define DENSE(OFS, DB) do { \
    _Pragma("unroll") for (int mt = 0; mt < 4; mt++) acc[mt] = *(const f32x4*)((DB) + 16*mt + 4*g); \
    _Pragma("unroll") for (int mt = 0; mt < 4; mt++) acc[mt] = MFMA16(wf[((OFS) + mt*2)*64 + lane], a2[0], acc[mt]); \
    _Pragma("unroll") for (int mt = 0; mt < 4; mt++) acc[mt] = MFMA16(wf[((OFS) + mt*2 + 1)*64 + lane], a2[1], acc[mt]); \
    REPACK(); \
} while (0)

__global__ __launch_bounds__(256) void k_dec(
    const float* __restrict__ z, const int* __restrict__ ei,
    const unsigned short* __restrict__ wfrag,
    const float* __restrict__ db0, const float* __restrict__ db1,
    const float* __restrict__ db2, const float* __restrict__ db3,
    const float* __restrict__ db4,
    float* __restrict__ out, int E, int T, int totalTiles)
{
    int wid = blockIdx.x * 4 + (threadIdx.x >> 6);
    int lane = threadIdx.x & 63;
    int g = lane >> 4, c = lane & 15;
    int t0 = wid * T;
    if (t0 >= totalTiles) return;
    int t1 = min(t0 + T, totalTiles);

    const short8* wf = (const short8*)wfrag;

    int eiOfs = (g < 2) ? 0 : E;
    int zofs = (g & 1) * 8;

    int node = ei[eiOfs + min(t0 * 16 + c, E - 1)];
    f32x4 zv0 = *(const f32x4*)(z + (size_t)node * 16 + zofs);
    f32x4 zv1 = *(const f32x4*)(z + (size_t)node * 16 + zofs + 4);
    int node_n = 0;
    if (t0 + 1 < t1) node_n = ei[eiOfs + min((t0 + 1) * 16 + c, E - 1)];

    for (int t = t0; t < t1; ++t) {
        f32x4 zn0 = {0.f,0.f,0.f,0.f}, zn1 = {0.f,0.f,0.f,0.f};
        if (t + 1 < t1) {
            zn0 = *(const f32x4*)(z + (size_t)node_n * 16 + zofs);
            zn1 = *(const f32x4*)(z + (size_t)node_n * 16 + zofs + 4);
        }
        int node_nn = 0;
        if (t + 2 < t1) node_nn = ei[eiOfs + min((t + 2) * 16 + c, E - 1)];

        short8 af0;
        #pragma unroll
        for (int j = 0; j < 4; j++) {
            af0[j]     = (short)f2bf(zv0[j]);
            af0[4 + j] = (short)f2bf(zv1[j]);
        }
        f32x4 acc[4];
        short8 a2[2];
        #pragma unroll
        for (int mt = 0; mt < 4; mt++) acc[mt] = *(const f32x4*)(db0 + 16*mt + 4*g);
        #pragma unroll
        for (int mt = 0; mt < 4; mt++) acc[mt] = MFMA16(wf[mt*64 + lane], af0, acc[mt]);
        REPACK();

        DENSE(4,  db1);
        DENSE(12, db2);
        DENSE(20, db3);

        f32x4 o4;
        if (g < 2) o4 = *(const f32x4*)(db4 + 4*g);
        else { o4[0]=0.f; o4[1]=0.f; o4[2]=0.f; o4[3]=0.f; }
        o4 = MFMA16(wf[28*64 + lane], a2[0], o4);
        o4 = MFMA16(wf[29*64 + lane], a2[1], o4);

        int e = t * 16 + c;
        if (g < 2 && e < E) *(f32x4*)(out + (size_t)e * 8 + 4*g) = o4;

        zv0 = zn0; zv1 = zn1; node_n = node_nn;
    }
}

// ---------------- launch ----------------
extern "C" void kernel_launch(void* const* d_in, const int* in_sizes, int n_in,
                              void* d_out, int out_size, void* d_ws, size_t ws_size,
                              hipStream_t stream)
{
    const float* x   = (const float*)d_in[0];
    const int*   ei  = (const int*)d_in[1];
    const float* ea  = (const float*)d_in[2];
    const float* eps = (const float*)d_in[3];
    const float* w1  = (const float*)d_in[4];
    const float* b1  = (const float*)d_in[5];
    const float* w2  = (const float*)d_in[6];
    const float* b2  = (const float*)d_in[7];
    const float* root[4]; const float* cb[4]; const float* g[4]; const float* be[4];
    for (int l = 0; l < 4; l++) {
        root[l] = (const float*)d_in[8 + 4*l];
        cb[l]   = (const float*)d_in[9 + 4*l];
        g[l]    = (const float*)d_in[10 + 4*l];
        be[l]   = (const float*)d_in[11 + 4*l];
    }
    const float* mu_w = (const float*)d_in[24];
    const float* mu_b = (const float*)d_in[25];
    const float* lv_w = (const float*)d_in[26];
    const float* lv_b = (const float*)d_in[27];
    const float* dw[5]; const float* db[5];
    for (int i = 0; i < 5; i++) {
        dw[i] = (const float*)d_in[28 + 2*i];
        db[i] = (const float*)d_in[29 + 2*i];
    }
    float* out = (float*)d_out;

    int N = in_sizes[0] / 16;
    int E = in_sizes[2] / 8;
    float invN = 1.0f / N;

    // ---- workspace layout ----
    int*   cnt      = (int*)d_ws;                       // N
    float* statsRep = (float*)(cnt + N);                // 4 x NREP x 32
    int*   offs     = (int*)(statsRep + 4 * NREP * 32); // N
    int*   bsum     = offs + N;                         // 256
    int*   slotOf   = bsum + 256;                       // E (rank, then slot)
    int*   srcSl    = slotOf + E;                       // E
    unsigned int* aP  = (unsigned int*)(srcSl + E);     // E*16 (packed)
    unsigned int* xP  = aP + (size_t)E * 16;            // N*16 (packed)
    unsigned int* hA  = xP + (size_t)N * 16;            // N*16 (packed)
    unsigned int* hB  = hA + (size_t)N * 16;            // N*16 (packed)
    float* zbuf     = (float*)(hB + (size_t)N * 16);    // N*16
    unsigned short* wfrag  = (unsigned short*)(zbuf + (size_t)N * 16); // 15360
    unsigned short* wfrag2 = wfrag + 15360;             // 36864

    int nbScan = (N + 255) / 256;

    (void)hipMemsetAsync(cnt, 0, ((size_t)N + 4 * NREP * 32) * sizeof(int), stream);

    k_wpreps<<<17, 256, 0, stream>>>(dw[0], dw[1], dw[2], dw[3], dw[4], wfrag,
                                     w2, b2, root[0], root[1], root[2], root[3], wfrag2);
    k_pack<<<(N * 16 + 255) / 256, 256, 0, stream>>>(x, xP, N * 16);

    k_fillR<<<(E + 255) / 256, 256, 0, stream>>>(ei, cnt, slotOf, E);
    k_scanA<<<nbScan, 256, 0, stream>>>(cnt, offs, bsum, N);
    k_scanB<<<1, 256, 0, stream>>>(bsum, nbScan);
    k_scanC<<<nbScan, 256, 0, stream>>>(offs, bsum, N);
    k_scatter<<<(E + 255) / 256, 256, 0, stream>>>(ei, offs, slotOf, srcSl, E);

    k_a<<<(E + 255) / 256, 256, 0, stream>>>(ea, w1, b1, slotOf, aP, E);

    int nbF = (N + 15) / 16;
    float* sr0 = statsRep + 0 * NREP * 32;
    float* sr1 = statsRep + 1 * NREP * 32;
    float* sr2 = statsRep + 2 * NREP * 32;
    float* sr3 = statsRep + 3 * NREP * 32;

    k_fuse3<0><<<nbF, 256, 0, stream>>>(xP, nullptr, nullptr, nullptr,
                                        offs, cnt, srcSl, aP,
                                        wfrag2 + 0 * 9216, cb[0], hA, sr0, N, invN);
    k_fuse3<1><<<nbF, 256, 0, stream>>>(hA, sr0, g[0], be[0],
                                        offs, cnt, srcSl, aP,
                                        wfrag2 + 1 * 9216, cb[1], hB, sr1, N, invN);
    k_fuse3<1><<<nbF, 256, 0, stream>>>(hB, sr1, g[1], be[1],
                                        offs, cnt, srcSl, aP,
                                        wfrag2 + 2 * 9216, cb[2], hA, sr2, N, invN);
    k_fuse3<1><<<nbF, 256, 0, stream>>>(hA, sr2, g[2], be[2],
                                        offs, cnt, srcSl, aP,
                                        wfrag2 + 3 * 9216, cb[3], hB, sr3, N, invN);

    k_z<<<(N * 16 + 255) / 256, 256, 0, stream>>>(hB, sr3, g[3], be[3],
                                                  mu_w, mu_b, lv_w, lv_b, eps, zbuf, N, invN);

    // decoder: R13 config (T~13 tiles/wave, ~962 blocks) — measured optimum
    int totalTiles = (E + 15) >> 4;
    int T = (totalTiles + 4095) / 4096;
    int wavesUsed = (totalTiles + T - 1) / T;
    int blocks = (wavesUsed + 3) / 4;
    k_dec<<<blocks, 256, 0, stream>>>(zbuf, ei, wfrag,
        db[0], db[1], db[2], db[3], db[4], out, E, T, totalTiles);
}